// Round 1
// baseline (558.319 us; speedup 1.0000x reference)
//
#include <hip/hip_runtime.h>

#define BATCH 1024
#define DMODEL 1024
#define HEADS 16

typedef short bh8 __attribute__((ext_vector_type(8)));
typedef float f4 __attribute__((ext_vector_type(4)));
typedef unsigned short u16x4 __attribute__((ext_vector_type(4)));

__device__ inline unsigned short f2b(float f) {
  union { float f; unsigned int u; } x; x.f = f;
  unsigned int r = x.u + 0x7fffu + ((x.u >> 16) & 1u);
  return (unsigned short)(r >> 16);
}

// ---- fp32 -> bf16 convert (4 elems/thread) ----
__global__ __launch_bounds__(256)
void cvt_bf16_kernel(const float* __restrict__ in, unsigned short* __restrict__ out, int n4) {
  int i = blockIdx.x * 256 + threadIdx.x;
  if (i >= n4) return;
  const float4 f = ((const float4*)in)[i];
  u16x4 h = { f2b(f.x), f2b(f.y), f2b(f.z), f2b(f.w) };
  ((u16x4*)out)[i] = h;
}

// ---- fp32 [R][C] -> bf16 transposed [C][R] ----
__global__ __launch_bounds__(256)
void transpose_cvt_kernel(const float* __restrict__ in, unsigned short* __restrict__ out,
                          int R, int C) {
  __shared__ float t[32][33];
  int c0 = blockIdx.x * 32, r0 = blockIdx.y * 32;
  int tx = threadIdx.x, ty = threadIdx.y;
  #pragma unroll
  for (int i = ty; i < 32; i += 8)
    t[i][tx] = in[(size_t)(r0 + i) * C + c0 + tx];
  __syncthreads();
  #pragma unroll
  for (int i = ty; i < 32; i += 8)
    out[(size_t)(c0 + i) * R + r0 + tx] = f2b(t[tx][i]);
}

// ---- beta = sigmoid(x @ Wg), one block per batch row ----
__global__ __launch_bounds__(256)
void beta_kernel(const float* __restrict__ x, const float* __restrict__ Wg,
                 float* __restrict__ beta) {
  __shared__ float xr[DMODEL];
  int b = blockIdx.x;
  for (int i = threadIdx.x; i < DMODEL; i += 256) xr[i] = x[(size_t)b * DMODEL + i];
  __syncthreads();
  int wid = threadIdx.x >> 6, lane = threadIdx.x & 63;
  #pragma unroll
  for (int hh = 0; hh < 4; ++hh) {
    int h = wid * 4 + hh;
    float p = 0.f;
    for (int i = lane; i < DMODEL; i += 64) p += xr[i] * Wg[(size_t)i * HEADS + h];
    #pragma unroll
    for (int off = 32; off > 0; off >>= 1) p += __shfl_down(p, off, 64);
    if (lane == 0) beta[b * HEADS + h] = 1.f / (1.f + __expf(-p));
  }
}

// ---- bf16 MFMA GEMM: C[M][N] = A[M][K] @ Bt[N][K]^T (+bias) ----
// A, Bt bf16 row-major with K contiguous; C fp32. 256 threads, 2x2 waves.
template<int BM, int BN>
__global__ __launch_bounds__(256)
void gemm_tn(const unsigned short* __restrict__ A, const unsigned short* __restrict__ Bt,
             float* __restrict__ C, const float* __restrict__ bias, int N, int K) {
  constexpr int BK = 32;
  constexpr int LD = BK + 8;     // +16B pad: conflict-free b128 frag reads
  constexpr int TM = BM / 32;    // 16-tiles per wave in m
  constexpr int TN = BN / 32;
  __shared__ unsigned short As[BM * LD];
  __shared__ unsigned short Bs[BN * LD];
  const int tid = threadIdx.x;
  const int lane = tid & 63;
  const int wid = tid >> 6;
  const int wm = wid >> 1, wn = wid & 1;
  const int m0 = blockIdx.y * BM, n0 = blockIdx.x * BN;
  const int row16 = lane & 15;
  const int quad = lane >> 4;
  const int s_chunk = tid & 3, s_row = tid >> 2;

  f4 acc[TM][TN];
  #pragma unroll
  for (int i = 0; i < TM; ++i)
    #pragma unroll
    for (int j = 0; j < TN; ++j)
      acc[i][j] = f4{0.f, 0.f, 0.f, 0.f};

  for (int k0 = 0; k0 < K; k0 += BK) {
    #pragma unroll
    for (int p = 0; p < BM / 64; ++p) {
      int r = s_row + p * 64;
      bh8 v = *(const bh8*)(A + (size_t)(m0 + r) * K + k0 + s_chunk * 8);
      *(bh8*)(&As[r * LD + s_chunk * 8]) = v;
    }
    #pragma unroll
    for (int p = 0; p < BN / 64; ++p) {
      int r = s_row + p * 64;
      bh8 v = *(const bh8*)(Bt + (size_t)(n0 + r) * K + k0 + s_chunk * 8);
      *(bh8*)(&Bs[r * LD + s_chunk * 8]) = v;
    }
    __syncthreads();
    bh8 af[TM], bfr[TN];
    #pragma unroll
    for (int i = 0; i < TM; ++i)
      af[i] = *(const bh8*)(&As[(wm * (BM / 2) + i * 16 + row16) * LD + quad * 8]);
    #pragma unroll
    for (int j = 0; j < TN; ++j)
      bfr[j] = *(const bh8*)(&Bs[(wn * (BN / 2) + j * 16 + row16) * LD + quad * 8]);
    #pragma unroll
    for (int i = 0; i < TM; ++i)
      #pragma unroll
      for (int j = 0; j < TN; ++j)
        acc[i][j] = __builtin_amdgcn_mfma_f32_16x16x32_bf16(af[i], bfr[j], acc[i][j], 0, 0, 0);
    __syncthreads();
  }
  #pragma unroll
  for (int i = 0; i < TM; ++i) {
    #pragma unroll
    for (int j = 0; j < TN; ++j) {
      int col = n0 + wn * (BN / 2) + j * 16 + row16;
      float bv = bias ? bias[col] : 0.f;
      #pragma unroll
      for (int rg = 0; rg < 4; ++rg) {
        int row = m0 + wm * (BM / 2) + i * 16 + quad * 4 + rg;
        C[(size_t)row * N + col] = acc[i][j][rg] + bv;
      }
    }
  }
}

// ---- fast-weight delta-rule update: one block per (b,h) ----
// thread t: row r=t>>2 of the 64x64 W, 16-col segment q4=t&3
__global__ __launch_bounds__(256)
void fastweight_kernel(const float* __restrict__ Wf, const float* __restrict__ QKV,
                       const float* __restrict__ beta, float* __restrict__ newW,
                       unsigned short* __restrict__ hiddenh) {
  const int bh = blockIdx.x;
  const int b = bh >> 4, h = bh & 15;
  const int tid = threadIdx.x;
  const int r = tid >> 2, q4 = tid & 3;
  const float* base = QKV + (size_t)b * 3072 + h * 64;
  const float4* qp = (const float4*)base;
  const float4* kp = (const float4*)(base + 1024);
  const float* vp = base + 2048;
  const float be = beta[bh];
  const size_t woff = (size_t)bh * 4096 + (size_t)r * 64 + q4 * 16;
  const float4* wp = (const float4*)(Wf + woff);
  float4 w[4], kk[4];
  #pragma unroll
  for (int i = 0; i < 4; ++i) w[i] = wp[i];
  #pragma unroll
  for (int i = 0; i < 4; ++i) kk[i] = kp[q4 * 4 + i];
  float vex = 0.f;
  #pragma unroll
  for (int i = 0; i < 4; ++i)
    vex += w[i].x * kk[i].x + w[i].y * kk[i].y + w[i].z * kk[i].z + w[i].w * kk[i].w;
  vex += __shfl_xor(vex, 1, 64);
  vex += __shfl_xor(vex, 2, 64);
  const float dv = be * (vp[r] - vex);
  #pragma unroll
  for (int i = 0; i < 4; ++i) {
    w[i].x += dv * kk[i].x; w[i].y += dv * kk[i].y;
    w[i].z += dv * kk[i].z; w[i].w += dv * kk[i].w;
  }
  float4* op = (float4*)(newW + woff);
  #pragma unroll
  for (int i = 0; i < 4; ++i) op[i] = w[i];
  float o = 0.f;
  #pragma unroll
  for (int i = 0; i < 4; ++i) {
    float4 q = qp[q4 * 4 + i];
    o += w[i].x * q.x + w[i].y * q.y + w[i].z * q.z + w[i].w * q.w;
  }
  o += __shfl_xor(o, 1, 64);
  o += __shfl_xor(o, 2, 64);
  if (q4 == 0) hiddenh[(size_t)b * DMODEL + h * 64 + r] = f2b(o);
}

extern "C" void kernel_launch(void* const* d_in, const int* in_sizes, int n_in,
                              void* d_out, int out_size, void* d_ws, size_t ws_size,
                              hipStream_t stream) {
  const float* x  = (const float*)d_in[0];
  const float* Wf = (const float*)d_in[1];
  const float* Wq = (const float*)d_in[2];
  const float* Wk = (const float*)d_in[3];
  const float* Wv = (const float*)d_in[4];
  const float* Wg = (const float*)d_in[5];
  const float* Wo = (const float*)d_in[6];
  const float* bo = (const float*)d_in[7];
  float* out  = (float*)d_out;                       // [1024*1024]
  float* newW = out + (size_t)BATCH * DMODEL;        // [1024*16*64*64]

  // workspace layout (~24.1 MB)
  unsigned short* xh      = (unsigned short*)d_ws;                   // 2 MB
  unsigned short* WqkvT   = xh + (size_t)1024 * 1024;                // 6 MB
  unsigned short* WoT     = WqkvT + (size_t)3072 * 1024;             // 2 MB
  unsigned short* hiddenh = WoT + (size_t)1024 * 1024;               // 2 MB
  float* QKV   = (float*)(hiddenh + (size_t)1024 * 1024);            // 12 MB
  float* betab = QKV + (size_t)1024 * 3072;                          // 64 KB

  dim3 tb(32, 8);
  cvt_bf16_kernel<<<1024, 256, 0, stream>>>(x, xh, 1024 * 1024 / 4);
  transpose_cvt_kernel<<<dim3(32, 32), tb, 0, stream>>>(Wq, WqkvT,                    1024, 1024);
  transpose_cvt_kernel<<<dim3(32, 32), tb, 0, stream>>>(Wk, WqkvT + 1024 * 1024,      1024, 1024);
  transpose_cvt_kernel<<<dim3(32, 32), tb, 0, stream>>>(Wv, WqkvT + 2 * 1024 * 1024,  1024, 1024);
  transpose_cvt_kernel<<<dim3(32, 32), tb, 0, stream>>>(Wo, WoT,                      1024, 1024);
  beta_kernel<<<BATCH, 256, 0, stream>>>(x, Wg, betab);
  gemm_tn<64, 64><<<dim3(3072 / 64, 1024 / 64), 256, 0, stream>>>(xh, WqkvT, QKV, nullptr, 3072, 1024);
  fastweight_kernel<<<BATCH * HEADS, 256, 0, stream>>>(Wf, QKV, betab, newW, hiddenh);
  gemm_tn<64, 64><<<dim3(1024 / 64, 1024 / 64), 256, 0, stream>>>(hiddenh, WoT, out, bo, 1024, 1024);
}